// Round 1
// baseline (237.955 us; speedup 1.0000x reference)
//
#include <hip/hip_runtime.h>

typedef __attribute__((ext_vector_type(8))) short bf8v;   // 8 bf16 (4 VGPRs)
typedef __attribute__((ext_vector_type(4))) float f4v;    // MFMA acc
typedef unsigned short u16;
typedef unsigned int   u32;

__device__ inline u16 f2b(float f){
  u32 u = __builtin_bit_cast(u32, f);
  u += 0x7fffu + ((u >> 16) & 1u);     // RNE, no NaN expected
  return (u16)(u >> 16);
}

// ---------------- f32 -> bf16 conversion ----------------
__global__ void conv_f2b(const float* __restrict__ in, u16* __restrict__ out, int n4){
  int i = blockIdx.x * blockDim.x + threadIdx.x;
  int stride = gridDim.x * blockDim.x;
  for (; i < n4; i += stride){
    float4 v = ((const float4*)in)[i];
    uint2 r;
    r.x = (u32)f2b(v.x) | ((u32)f2b(v.y) << 16);
    r.y = (u32)f2b(v.z) | ((u32)f2b(v.w) << 16);
    ((uint2*)out)[i] = r;
  }
}

// ---------------- bt-GEMM: C[M,N] = A[M,K] * B[N,K]^T (bf16 in, f32/bf16 out) ----------------
template<int OUTBF>
__global__ __launch_bounds__(256) void gemm_bt(const u16* __restrict__ A, const u16* __restrict__ B,
                                               void* __restrict__ C, int M, int N, int K){
  __shared__ u16 At[128][40];   // +8 pad: row stride 80 B -> max 2-way conflict
  __shared__ u16 Bt[128][40];
  const int tid = threadIdx.x;
  const int l = tid & 63, w = tid >> 6;
  const int m0 = blockIdx.y * 128, n0 = blockIdx.x * 128;
  const int wrow = (w >> 1) * 64, wcol = (w & 1) * 64;
  f4v acc[4][4];
  #pragma unroll
  for (int a = 0; a < 4; a++)
    #pragma unroll
    for (int b = 0; b < 4; b++) acc[a][b] = (f4v)0.0f;

  const int srow = tid >> 2, sseg = tid & 3;
  for (int k0 = 0; k0 < K; k0 += 32){
    #pragma unroll
    for (int p = 0; p < 2; p++){
      int r = p * 64 + srow;
      *(int4*)((char*)&At[0][0] + r * 80 + sseg * 16) =
          *(const int4*)(A + (size_t)(m0 + r) * K + k0 + sseg * 8);
      *(int4*)((char*)&Bt[0][0] + r * 80 + sseg * 16) =
          *(const int4*)(B + (size_t)(n0 + r) * K + k0 + sseg * 8);
    }
    __syncthreads();
    bf8v af[4], bfr[4];
    #pragma unroll
    for (int mr = 0; mr < 4; mr++)
      af[mr] = *(const bf8v*)((const char*)&At[0][0] + (wrow + mr * 16 + (l & 15)) * 80 + (l >> 4) * 16);
    #pragma unroll
    for (int nc = 0; nc < 4; nc++)
      bfr[nc] = *(const bf8v*)((const char*)&Bt[0][0] + (wcol + nc * 16 + (l & 15)) * 80 + (l >> 4) * 16);
    #pragma unroll
    for (int mr = 0; mr < 4; mr++)
      #pragma unroll
      for (int nc = 0; nc < 4; nc++)
        acc[mr][nc] = __builtin_amdgcn_mfma_f32_16x16x32_bf16(af[mr], bfr[nc], acc[mr][nc], 0, 0, 0);
    __syncthreads();
  }
  #pragma unroll
  for (int mr = 0; mr < 4; mr++)
    #pragma unroll
    for (int nc = 0; nc < 4; nc++)
      #pragma unroll
      for (int rr = 0; rr < 4; rr++){
        int row = m0 + wrow + mr * 16 + (l >> 4) * 4 + rr;
        int col = n0 + wcol + nc * 16 + (l & 15);
        if (OUTBF) ((u16*)C)[(size_t)row * N + col] = f2b(acc[mr][nc][rr]);
        else       ((float*)C)[(size_t)row * N + col] = acc[mr][nc][rr];
      }
}

// ---------------- ReLU + top-32-of-128 sparsify (one wave per (t,h) row) ----------------
// in:  q f32 [T][H*128] ; out: bf16 [H][T][128] (non-top-k zeroed)
__global__ __launch_bounds__(256) void topk_kernel(const float* __restrict__ qin, u16* __restrict__ qout){
  int w = threadIdx.x >> 6, l = threadIdx.x & 63;
  int row = blockIdx.x * 4 + w;          // row = t*16 + h
  int t = row >> 4, h = row & 15;
  const float* src = qin + (size_t)t * 2048 + h * 128 + l * 2;
  float v0 = src[0], v1 = src[1];
  v0 = v0 > 0.f ? v0 : 0.f;
  v1 = v1 > 0.f ? v1 : 0.f;
  u32 u0 = __builtin_bit_cast(u32, v0), u1 = __builtin_bit_cast(u32, v1);
  // radix-select the 32nd largest (positive float bits are order-isomorphic to uint)
  u32 pre = 0;
  for (int b = 30; b >= 0; --b){
    u32 cand = pre | (1u << b);
    int c = __builtin_popcountll(__ballot(u0 >= cand)) + __builtin_popcountll(__ballot(u1 >= cand));
    if (c >= 32) pre = cand;
  }
  u16 o0 = (u0 >= pre) ? f2b(v0) : (u16)0;
  u16 o1 = (u1 >= pre) ? f2b(v1) : (u16)0;
  ((u32*)(qout + ((size_t)h * 2048 + t) * 128))[l] = (u32)o0 | ((u32)o1 << 16);
}

// ---------------- fused causal p=1-normalized attention ----------------
// qs/ks: bf16 [H][T][128]; v: bf16 [T][H*64]; out Y: bf16 [T][H*64]
__global__ __launch_bounds__(256) void attn_kernel(const u16* __restrict__ qs, const u16* __restrict__ ks,
                                                   const u16* __restrict__ vb, const float* __restrict__ sink,
                                                   const float* __restrict__ logbeta, u16* __restrict__ yout){
  __shared__ u16 Kt[64][136];  // [kv-row][128+8]  (stride 272 B)
  __shared__ u16 Vt[64][72];   // transposed: [d][kv-row] (stride 144 B)
  __shared__ u16 St[64][72];   // per-wave 16-row S slabs (stride 144 B)
  const int tid = threadIdx.x, l = tid & 63, w = tid >> 6;
  const int it = blockIdx.x & 31, h = blockIdx.x >> 5;
  const float beta = expf(logbeta[0]);

  // Q fragments for this wave's 16 rows, kept in registers across the KV loop
  bf8v qf[4];
  {
    int t = it * 64 + w * 16 + (l & 15);
    const u16* qrow = qs + ((size_t)h * 2048 + t) * 128 + (l >> 4) * 8;
    #pragma unroll
    for (int kk = 0; kk < 4; kk++) qf[kk] = *(const bf8v*)(qrow + kk * 32);
  }

  f4v accY[4];
  #pragma unroll
  for (int c = 0; c < 4; c++) accY[c] = (f4v)0.0f;
  float dsum[4] = {0.f, 0.f, 0.f, 0.f};

  for (int jt = 0; jt <= it; ++jt){
    __syncthreads();   // protect Kt/Vt from previous iteration's readers
    // stage K tile (64 x 128)
    #pragma unroll
    for (int p = 0; p < 4; p++){
      int ch = p * 256 + tid;
      int r = ch >> 4, seg = ch & 15;
      *(int4*)((char*)&Kt[0][0] + r * 272 + seg * 16) =
          *(const int4*)(ks + ((size_t)h * 2048 + jt * 64 + r) * 128 + seg * 8);
    }
    // stage V tile transposed (Vt[d][j])
    {
      int j = tid & 63, dblk = tid >> 6;
      #pragma unroll
      for (int hf = 0; hf < 2; hf++){
        int d0 = dblk * 16 + hf * 8;
        union { int4 v; u16 u[8]; } tmp;
        tmp.v = *(const int4*)(vb + (size_t)(jt * 64 + j) * 1024 + h * 64 + d0);
        #pragma unroll
        for (int e = 0; e < 8; e++) Vt[d0 + e][j] = tmp.u[e];
      }
    }
    __syncthreads();

    // S = Qs * Ks^T  (64x64 tile; this wave: rows w*16..w*16+15)
    f4v accS[4];
    #pragma unroll
    for (int c = 0; c < 4; c++) accS[c] = (f4v)0.0f;
    #pragma unroll
    for (int c = 0; c < 4; c++)
      #pragma unroll
      for (int kk = 0; kk < 4; kk++){
        bf8v kf = *(const bf8v*)((const char*)&Kt[0][0] + (c * 16 + (l & 15)) * 272 + kk * 64 + (l >> 4) * 16);
        accS[c] = __builtin_amdgcn_mfma_f32_16x16x32_bf16(qf[kk], kf, accS[c], 0, 0, 0);
      }
    // causal mask on the diagonal tile
    if (jt == it){
      #pragma unroll
      for (int c = 0; c < 4; c++)
        #pragma unroll
        for (int rr = 0; rr < 4; rr++){
          int i = w * 16 + (l >> 4) * 4 + rr;
          int j = c * 16 + (l & 15);
          if (j > i) accS[c][rr] = 0.f;
        }
    }
    // row-sum (f32) + S -> bf16 into per-wave LDS slab
    #pragma unroll
    for (int c = 0; c < 4; c++)
      #pragma unroll
      for (int rr = 0; rr < 4; rr++){
        dsum[rr] += accS[c][rr];
        St[w * 16 + (l >> 4) * 4 + rr][c * 16 + (l & 15)] = f2b(accS[c][rr]);
      }
    __syncthreads();   // drains St writes (and keeps waves phase-locked)

    // Yacc += S * V   (K = 64)
    #pragma unroll
    for (int k2 = 0; k2 < 2; k2++){
      bf8v afr = *(const bf8v*)((const char*)&St[0][0] + (w * 16 + (l & 15)) * 144 + k2 * 64 + (l >> 4) * 16);
      #pragma unroll
      for (int c = 0; c < 4; c++){
        bf8v vfr = *(const bf8v*)((const char*)&Vt[0][0] + (c * 16 + (l & 15)) * 144 + k2 * 64 + (l >> 4) * 16);
        accY[c] = __builtin_amdgcn_mfma_f32_16x16x32_bf16(afr, vfr, accY[c], 0, 0, 0);
      }
    }
  }

  // reduce dsum over the 16-lane column groups -> full row sums
  #pragma unroll
  for (int rr = 0; rr < 4; rr++){
    float s = dsum[rr];
    s += __shfl_xor(s, 1, 64);
    s += __shfl_xor(s, 2, 64);
    s += __shfl_xor(s, 4, 64);
    s += __shfl_xor(s, 8, 64);
    dsum[rr] = s;
  }
  // normalize + sink, store Y bf16 [T][H*64]
  #pragma unroll
  for (int c = 0; c < 4; c++){
    float sv = sink[h * 64 + c * 16 + (l & 15)];
    #pragma unroll
    for (int rr = 0; rr < 4; rr++){
      float den = dsum[rr] + beta;
      float inv = 1.0f / fmaxf(den, 1e-12f);
      float y = (accY[c][rr] + beta * sv) * inv;
      int row = it * 64 + w * 16 + (l >> 4) * 4 + rr;
      yout[(size_t)row * 1024 + h * 64 + c * 16 + (l & 15)] = f2b(y);
    }
  }
}

extern "C" void kernel_launch(void* const* d_in, const int* in_sizes, int n_in,
                              void* d_out, int out_size, void* d_ws, size_t ws_size,
                              hipStream_t stream){
  const float* x    = (const float*)d_in[0];
  const float* Wq   = (const float*)d_in[1];
  const float* Wk   = (const float*)d_in[2];
  const float* Wv   = (const float*)d_in[3];
  const float* Wo   = (const float*)d_in[4];
  const float* sink = (const float*)d_in[5];
  const float* logb = (const float*)d_in[6];

  char* ws = (char*)d_ws;
  u16*   xb  = (u16*)(ws + 0);           // 4 MB  x bf16 [2048][1024]
  u16*   wqb = (u16*)(ws + 4194304);     // 4 MB
  u16*   wkb = (u16*)(ws + 8388608);     // 4 MB
  u16*   wvb = (u16*)(ws + 12582912);    // 2 MB
  u16*   wob = (u16*)(ws + 14680064);    // 2 MB
  float* qf  = (float*)(ws + 16777216);  // 16 MB q f32 [2048][2048]
  float* kf  = (float*)(ws + 33554432);  // 16 MB
  u16*   qsb = (u16*)(ws + 50331648);    // 8 MB  qs bf16 [16][2048][128]
  u16*   ksb = (u16*)(ws + 58720256);    // 8 MB
  u16*   vbb = (u16*)(ws + 67108864);    // 4 MB  v bf16 [2048][1024]
  u16*   yb  = (u16*)(ws + 71303168);    // 4 MB  Y bf16 [2048][1024]

  conv_f2b<<<1024, 256, 0, stream>>>(x,  xb,  2097152 / 4);
  conv_f2b<<<1024, 256, 0, stream>>>(Wq, wqb, 2097152 / 4);
  conv_f2b<<<1024, 256, 0, stream>>>(Wk, wkb, 2097152 / 4);
  conv_f2b<<<1024, 256, 0, stream>>>(Wv, wvb, 1048576 / 4);
  conv_f2b<<<1024, 256, 0, stream>>>(Wo, wob, 1048576 / 4);

  gemm_bt<0><<<dim3(16, 16), 256, 0, stream>>>(xb, wqb, qf,  2048, 2048, 1024);
  gemm_bt<0><<<dim3(16, 16), 256, 0, stream>>>(xb, wkb, kf,  2048, 2048, 1024);
  gemm_bt<1><<<dim3(8, 16),  256, 0, stream>>>(xb, wvb, vbb, 2048, 1024, 1024);

  topk_kernel<<<8192, 256, 0, stream>>>(qf, qsb);
  topk_kernel<<<8192, 256, 0, stream>>>(kf, ksb);

  attn_kernel<<<512, 256, 0, stream>>>(qsb, ksb, vbb, sink, logb, yb);

  gemm_bt<0><<<dim3(8, 16), 256, 0, stream>>>(yb, wob, (float*)d_out, 2048, 1024, 1024);
}

// Round 2
// 190.294 us; speedup vs baseline: 1.2505x; 1.2505x over previous
//
#include <hip/hip_runtime.h>

typedef __attribute__((ext_vector_type(8))) short bf8v;   // 8 bf16 (4 VGPRs)
typedef __attribute__((ext_vector_type(4))) float f4v;    // MFMA acc
typedef unsigned short u16;
typedef unsigned int   u32;

__device__ inline u16 f2b(float f){
  u32 u = __builtin_bit_cast(u32, f);
  u += 0x7fffu + ((u >> 16) & 1u);     // RNE
  return (u16)(u >> 16);
}

// ---------------- merged f32 -> bf16 conversion (x, Wq, Wk, Wv, Wo) ----------------
__global__ __launch_bounds__(256) void conv_all(const float* __restrict__ x,  const float* __restrict__ wq,
                                                const float* __restrict__ wk, const float* __restrict__ wv,
                                                const float* __restrict__ wo,
                                                u16* xb, u16* wqb, u16* wkb, u16* wvb, u16* wob){
  int i = blockIdx.x * 256 + threadIdx.x;   // 2,097,152 float4-groups total
  const float* src; u16* dst; int off;
  if      (i <  524288){ src = x;  dst = xb;  off = i; }
  else if (i < 1048576){ src = wq; dst = wqb; off = i -  524288; }
  else if (i < 1572864){ src = wk; dst = wkb; off = i - 1048576; }
  else if (i < 1835008){ src = wv; dst = wvb; off = i - 1572864; }
  else                 { src = wo; dst = wob; off = i - 1835008; }
  float4 v = ((const float4*)src)[off];
  uint2 r;
  r.x = (u32)f2b(v.x) | ((u32)f2b(v.y) << 16);
  r.y = (u32)f2b(v.z) | ((u32)f2b(v.w) << 16);
  ((uint2*)dst)[off] = r;
}

// ---------------- bt-GEMM core: C[M,N] = A[M,K]*B[N,K]^T, 128x128 tile, BK=64 ----------------
// global_load_lds width-16 staging, XOR-swizzled LDS (linear dest + swizzled source + swizzled read)
__device__ __forceinline__ void gemm_core(const u16* __restrict__ A, const u16* __restrict__ B,
                                          void* __restrict__ C, int N, int K,
                                          int m0, int n0, int outbf, u16* At, u16* Bt){
  const int tid = threadIdx.x;
  const int l = tid & 63, w = tid >> 6;
  const int wrow = (w >> 1) * 64, wcol = (w & 1) * 64;
  f4v acc[4][4];
  #pragma unroll
  for (int a = 0; a < 4; a++)
    #pragma unroll
    for (int b = 0; b < 4; b++) acc[a][b] = (f4v)0.0f;

  const int crow = l >> 3;                      // 0..7 (also = row&7 for every chunk)
  const int ksrc = ((l & 7) ^ crow) * 8;        // swizzled source k-segment (elems)

  for (int k0 = 0; k0 < K; k0 += 64){
    const u16* Abase = A + (size_t)m0 * K + k0;
    const u16* Bbase = B + (size_t)n0 * K + k0;
    #pragma unroll
    for (int c = 0; c < 4; c++){
      int chunk = w * 4 + c;
      int row = chunk * 8 + crow;
      __builtin_amdgcn_global_load_lds(
          (const __attribute__((address_space(1))) void*)(Abase + (size_t)row * K + ksrc),
          (__attribute__((address_space(3))) void*)(At + chunk * 512), 16, 0, 0);
      __builtin_amdgcn_global_load_lds(
          (const __attribute__((address_space(1))) void*)(Bbase + (size_t)row * K + ksrc),
          (__attribute__((address_space(3))) void*)(Bt + chunk * 512), 16, 0, 0);
    }
    __syncthreads();   // drains vmcnt (global_load_lds) + makes LDS visible
    #pragma unroll
    for (int kk = 0; kk < 2; kk++){
      bf8v af[4], bfr[4];
      #pragma unroll
      for (int mr = 0; mr < 4; mr++){
        int row = wrow + mr * 16 + (l & 15);
        af[mr] = *(const bf8v*)(At + row * 64 + (((kk * 32 + (l >> 4) * 8)) ^ ((row & 7) * 8)));
      }
      #pragma unroll
      for (int nc = 0; nc < 4; nc++){
        int row = wcol + nc * 16 + (l & 15);
        bfr[nc] = *(const bf8v*)(Bt + row * 64 + (((kk * 32 + (l >> 4) * 8)) ^ ((row & 7) * 8)));
      }
      #pragma unroll
      for (int mr = 0; mr < 4; mr++)
        #pragma unroll
        for (int nc = 0; nc < 4; nc++)
          acc[mr][nc] = __builtin_amdgcn_mfma_f32_16x16x32_bf16(af[mr], bfr[nc], acc[mr][nc], 0, 0, 0);
    }
    __syncthreads();
  }
  #pragma unroll
  for (int mr = 0; mr < 4; mr++)
    #pragma unroll
    for (int nc = 0; nc < 4; nc++)
      #pragma unroll
      for (int rr = 0; rr < 4; rr++){
        int row = m0 + wrow + mr * 16 + (l >> 4) * 4 + rr;
        int col = n0 + wcol + nc * 16 + (l & 15);
        if (outbf) ((u16*)C)[(size_t)row * N + col] = f2b(acc[mr][nc][rr]);
        else       ((float*)C)[(size_t)row * N + col] = acc[mr][nc][rr];
      }
}

// one launch for Q, K, V projections (640 blocks): b<256 Q, <512 K, else V
__global__ __launch_bounds__(256) void qkv_gemm(const u16* __restrict__ xb,
                                                const u16* __restrict__ wqb, const u16* __restrict__ wkb,
                                                const u16* __restrict__ wvb,
                                                float* qf, float* kf, u16* vbb){
  __shared__ u16 At[8192], Bt[8192];
  int b = blockIdx.x;
  const u16* Bp; void* Cp; int N, sh, outbf;
  if (b < 256)      { Bp = wqb; Cp = qf;  N = 2048; sh = 4; outbf = 0; }
  else if (b < 512) { Bp = wkb; Cp = kf;  N = 2048; sh = 4; outbf = 0; b -= 256; }
  else              { Bp = wvb; Cp = vbb; N = 1024; sh = 3; outbf = 1; b -= 512; }
  int m0 = (b >> sh) * 128, n0 = (b & ((1 << sh) - 1)) * 128;
  gemm_core(xb, Bp, Cp, N, 1024, m0, n0, outbf, At, Bt);
}

__global__ __launch_bounds__(256) void o_gemm(const u16* __restrict__ yb, const u16* __restrict__ wob,
                                              float* out){
  __shared__ u16 At[8192], Bt[8192];
  int b = blockIdx.x;
  gemm_core(yb, wob, out, 1024, 1024, (b >> 3) * 128, (b & 7) * 128, 0, At, Bt);
}

// ---------------- merged ReLU + top-32-of-128 (Q and K in one launch) ----------------
__global__ __launch_bounds__(256) void topk2(const float* __restrict__ qf, const float* __restrict__ kf,
                                             u16* __restrict__ qsb, u16* __restrict__ ksb){
  int w = threadIdx.x >> 6, l = threadIdx.x & 63;
  int b = blockIdx.x;
  const float* src; u16* dst;
  if (b < 8192){ src = qf; dst = qsb; } else { src = kf; dst = ksb; b -= 8192; }
  int row = b * 4 + w;                  // row = t*16 + h
  int t = row >> 4, h = row & 15;
  const float* sp = src + (size_t)t * 2048 + h * 128 + l * 2;
  float v0 = sp[0], v1 = sp[1];
  v0 = v0 > 0.f ? v0 : 0.f;
  v1 = v1 > 0.f ? v1 : 0.f;
  u32 u0 = __builtin_bit_cast(u32, v0), u1 = __builtin_bit_cast(u32, v1);
  u32 pre = 0;
  for (int bb = 30; bb >= 0; --bb){
    u32 cand = pre | (1u << bb);
    int c = __builtin_popcountll(__ballot(u0 >= cand)) + __builtin_popcountll(__ballot(u1 >= cand));
    if (c >= 32) pre = cand;
  }
  u16 o0 = (u0 >= pre) ? f2b(v0) : (u16)0;
  u16 o1 = (u1 >= pre) ? f2b(v1) : (u16)0;
  ((u32*)(dst + ((size_t)h * 2048 + t) * 128))[l] = (u32)o0 | ((u32)o1 << 16);
}

// ---------------- chunk-parallel causal p=1 attention ----------------
// grid = 16 heads x 80 (it,chunk) units; chunk = 8 kv-tiles (512 cols)
__global__ __launch_bounds__(256) void attn2(const u16* __restrict__ qs, const u16* __restrict__ ks,
                                             const u16* __restrict__ vb, const float* __restrict__ sink,
                                             const float* __restrict__ logbeta, u16* __restrict__ yout,
                                             float* __restrict__ Yp, float* __restrict__ Dp){
  __shared__ u16 Kt[64][136];  // [kv-row][128+8] stride 272B (conflict-free: 17 slots mod 8 distinct)
  __shared__ u16 Vt[64][72];   // transposed [d][kv-row], stride 144B
  __shared__ u16 St[64][72];   // per-wave 16-row S slabs (wave-private -> no barrier)
  const int tid = threadIdx.x, l = tid & 63, w = tid >> 6;
  const int u = blockIdx.x % 80, h = blockIdx.x / 80;
  int it, chunk, nch;
  if (u < 8)      { it = u; chunk = 0; nch = 1; }
  else if (u < 24){ int r = u - 8;  it = 8  + (r >> 1); chunk = r & 1; nch = 2; }
  else if (u < 48){ int r = u - 24; it = 16 + r / 3;    chunk = r % 3; nch = 3; }
  else            { int r = u - 48; it = 24 + (r >> 2); chunk = r & 3; nch = 4; }
  const int jt0 = chunk * 8;
  const int jt1 = min(jt0 + 8, it + 1);
  const float beta = expf(logbeta[0]);

  // Q fragments (wave's 16 rows) in registers for the whole loop
  bf8v qfr[4];
  {
    int t = it * 64 + w * 16 + (l & 15);
    const u16* qrow = qs + ((size_t)h * 2048 + t) * 128 + (l >> 4) * 8;
    #pragma unroll
    for (int kk = 0; kk < 4; kk++) qfr[kk] = *(const bf8v*)(qrow + kk * 32);
  }

  f4v accY[4];
  #pragma unroll
  for (int c = 0; c < 4; c++) accY[c] = (f4v)0.0f;
  float dsum[4] = {0.f, 0.f, 0.f, 0.f};

  int4 kreg[4], vreg[2];
  const int sr = tid >> 4, sseg = tid & 15;      // K staging: 4 rows/thread-phase
  const int vj = tid & 63, vd = tid >> 6;        // V staging

  auto load_kv = [&](int jt){
    #pragma unroll
    for (int p = 0; p < 4; p++)
      kreg[p] = *(const int4*)(ks + ((size_t)h * 2048 + jt * 64 + p * 16 + sr) * 128 + sseg * 8);
    #pragma unroll
    for (int hf = 0; hf < 2; hf++)
      vreg[hf] = *(const int4*)(vb + (size_t)(jt * 64 + vj) * 1024 + h * 64 + vd * 16 + hf * 8);
  };
  auto write_kv = [&](){
    #pragma unroll
    for (int p = 0; p < 4; p++)
      *(int4*)((char*)&Kt[0][0] + (p * 16 + sr) * 272 + sseg * 16) = kreg[p];
    #pragma unroll
    for (int hf = 0; hf < 2; hf++){
      union { int4 v; u16 s[8]; } tmp; tmp.v = vreg[hf];
      int d0 = vd * 16 + hf * 8;
      #pragma unroll
      for (int e = 0; e < 8; e++) Vt[d0 + e][vj] = tmp.s[e];
    }
  };

  load_kv(jt0);
  write_kv();
  __syncthreads();

  for (int jt = jt0; jt < jt1; ++jt){
    bool pf = (jt + 1 < jt1);
    if (pf) load_kv(jt + 1);         // issue early: HBM latency hides under compute

    f4v accS[4];
    #pragma unroll
    for (int c = 0; c < 4; c++) accS[c] = (f4v)0.0f;
    #pragma unroll
    for (int c = 0; c < 4; c++)
      #pragma unroll
      for (int kk = 0; kk < 4; kk++){
        bf8v kfr = *(const bf8v*)((const char*)&Kt[0][0] + (c * 16 + (l & 15)) * 272 + kk * 64 + (l >> 4) * 16);
        accS[c] = __builtin_amdgcn_mfma_f32_16x16x32_bf16(qfr[kk], kfr, accS[c], 0, 0, 0);
      }
    if (jt == it){
      #pragma unroll
      for (int c = 0; c < 4; c++)
        #pragma unroll
        for (int rr = 0; rr < 4; rr++){
          int i = w * 16 + (l >> 4) * 4 + rr;
          int j = c * 16 + (l & 15);
          if (j > i) accS[c][rr] = 0.f;
        }
    }
    #pragma unroll
    for (int c = 0; c < 4; c++)
      #pragma unroll
      for (int rr = 0; rr < 4; rr++){
        dsum[rr] += accS[c][rr];
        St[w * 16 + (l >> 4) * 4 + rr][c * 16 + (l & 15)] = f2b(accS[c][rr]);
      }
    // PV: St is wave-private (rows w*16..+15) -> only compiler lgkmcnt, no barrier
    #pragma unroll
    for (int k2 = 0; k2 < 2; k2++){
      bf8v afr = *(const bf8v*)((const char*)&St[0][0] + (w * 16 + (l & 15)) * 144 + k2 * 64 + (l >> 4) * 16);
      #pragma unroll
      for (int c = 0; c < 4; c++){
        bf8v vfr = *(const bf8v*)((const char*)&Vt[0][0] + (c * 16 + (l & 15)) * 144 + k2 * 64 + (l >> 4) * 16);
        accY[c] = __builtin_amdgcn_mfma_f32_16x16x32_bf16(afr, vfr, accY[c], 0, 0, 0);
      }
    }
    if (pf){
      __syncthreads();   // everyone done reading Kt/Vt
      write_kv();
      __syncthreads();   // next tile visible
    }
  }

  // reduce dsum over the 16 col-lanes
  #pragma unroll
  for (int rr = 0; rr < 4; rr++){
    float s = dsum[rr];
    s += __shfl_xor(s, 1, 64);
    s += __shfl_xor(s, 2, 64);
    s += __shfl_xor(s, 4, 64);
    s += __shfl_xor(s, 8, 64);
    dsum[rr] = s;
  }

  if (nch == 1){
    // finalize directly
    #pragma unroll
    for (int c = 0; c < 4; c++){
      float sv = sink[h * 64 + c * 16 + (l & 15)];
      #pragma unroll
      for (int rr = 0; rr < 4; rr++){
        float den = dsum[rr] + beta;
        float inv = 1.0f / fmaxf(den, 1e-12f);
        float y = (accY[c][rr] + beta * sv) * inv;
        int row = it * 64 + w * 16 + (l >> 4) * 4 + rr;
        yout[(size_t)row * 1024 + h * 64 + c * 16 + (l & 15)] = f2b(y);
      }
    }
  } else {
    // write f32 partials, packed by (h, u)
    float* yp = Yp + ((size_t)h * 80 + u) * 4096;
    #pragma unroll
    for (int c = 0; c < 4; c++)
      #pragma unroll
      for (int rr = 0; rr < 4; rr++){
        int row = w * 16 + (l >> 4) * 4 + rr;
        int col = c * 16 + (l & 15);
        yp[row * 64 + col] = accY[c][rr];
      }
    if ((l & 15) == 0){
      #pragma unroll
      for (int rr = 0; rr < 4; rr++)
        Dp[((size_t)h * 80 + u) * 64 + w * 16 + (l >> 4) * 4 + rr] = dsum[rr];
    }
  }
}

// combine partials for it >= 8 (grid 16 x 24)
__global__ __launch_bounds__(256) void attn_reduce(const float* __restrict__ Yp, const float* __restrict__ Dp,
                                                   const float* __restrict__ sink, const float* __restrict__ logbeta,
                                                   u16* __restrict__ yout){
  int blk = blockIdx.x;
  int h = blk / 24, it = 8 + blk % 24;
  int g = it >> 3;                               // 1..3
  int u0 = (g == 1 ? 8 : (g == 2 ? 24 : 48)) + (it - 8 * g) * (g + 1);
  int nch = g + 1;
  float beta = expf(logbeta[0]);
  __shared__ float inv_s[64];
  int t = threadIdx.x;
  if (t < 64){
    float s = 0.f;
    for (int c = 0; c < nch; c++) s += Dp[((size_t)h * 80 + u0 + c) * 64 + t];
    inv_s[t] = 1.0f / fmaxf(s + beta, 1e-12f);
  }
  __syncthreads();
  const float* base = Yp + ((size_t)h * 80 + u0) * 4096;
  #pragma unroll
  for (int e = 0; e < 16; e++){
    int idx = e * 256 + t;
    float acc = 0.f;
    for (int c = 0; c < nch; c++) acc += base[c * 4096 + idx];
    int row = idx >> 6, col = idx & 63;
    float y = (acc + beta * sink[h * 64 + col]) * inv_s[row];
    yout[(size_t)(it * 64 + row) * 1024 + h * 64 + col] = f2b(y);
  }
}

extern "C" void kernel_launch(void* const* d_in, const int* in_sizes, int n_in,
                              void* d_out, int out_size, void* d_ws, size_t ws_size,
                              hipStream_t stream){
  const float* x    = (const float*)d_in[0];
  const float* Wq   = (const float*)d_in[1];
  const float* Wk   = (const float*)d_in[2];
  const float* Wv   = (const float*)d_in[3];
  const float* Wo   = (const float*)d_in[4];
  const float* sink = (const float*)d_in[5];
  const float* logb = (const float*)d_in[6];

  char* ws = (char*)d_ws;
  u16*   xb  = (u16*)(ws + 0);            // 4 MB
  u16*   wqb = (u16*)(ws + 4194304);      // 4 MB
  u16*   wkb = (u16*)(ws + 8388608);      // 4 MB
  u16*   wvb = (u16*)(ws + 12582912);     // 2 MB
  u16*   wob = (u16*)(ws + 14680064);     // 2 MB
  float* qf  = (float*)(ws + 16777216);   // 16 MB (dead after topk; reused by Yp)
  float* kf  = (float*)(ws + 33554432);   // 16 MB (dead after topk; reused by Dp)
  u16*   qsb = (u16*)(ws + 50331648);     // 8 MB  [16][2048][128]
  u16*   ksb = (u16*)(ws + 58720256);     // 8 MB
  u16*   vbb = (u16*)(ws + 67108864);     // 4 MB  [2048][1024]
  u16*   yb  = (u16*)(ws + 71303168);     // 4 MB  [2048][1024]
  float* Yp  = (float*)(ws + 16777216);   // 21 MB packed partials (over qf)
  float* Dp  = (float*)(ws + 37748736);   // 328 KB (inside dead kf)

  conv_all<<<8192, 256, 0, stream>>>(x, Wq, Wk, Wv, Wo, xb, wqb, wkb, wvb, wob);
  qkv_gemm<<<640, 256, 0, stream>>>(xb, wqb, wkb, wvb, qf, kf, vbb);
  topk2<<<16384, 256, 0, stream>>>(qf, kf, qsb, ksb);
  attn2<<<1280, 256, 0, stream>>>(qsb, ksb, vbb, sink, logb, yb, Yp, Dp);
  attn_reduce<<<384, 256, 0, stream>>>(Yp, Dp, sink, logb, yb);
  o_gemm<<<128, 256, 0, stream>>>(yb, wob, (float*)d_out);
}

// Round 3
// 176.843 us; speedup vs baseline: 1.3456x; 1.0761x over previous
//
#include <hip/hip_runtime.h>

typedef __attribute__((ext_vector_type(8))) short bf8v;   // 8 bf16 (4 VGPRs)
typedef __attribute__((ext_vector_type(4))) float f4v;    // MFMA acc
typedef unsigned short u16;
typedef unsigned int   u32;
#define AS1 __attribute__((address_space(1)))
#define AS3 __attribute__((address_space(3)))

__device__ inline u16 f2b(float f){
  u32 u = __builtin_bit_cast(u32, f);
  u += 0x7fffu + ((u >> 16) & 1u);     // RNE
  return (u16)(u >> 16);
}

// ---------------- merged f32 -> bf16 conversion (x, Wq, Wk, Wv, Wo) ----------------
__global__ __launch_bounds__(256) void conv_all(const float* __restrict__ x,  const float* __restrict__ wq,
                                                const float* __restrict__ wk, const float* __restrict__ wv,
                                                const float* __restrict__ wo,
                                                u16* xb, u16* wqb, u16* wkb, u16* wvb, u16* wob){
  int i = blockIdx.x * 256 + threadIdx.x;
  const float* src; u16* dst; int off;
  if      (i <  524288){ src = x;  dst = xb;  off = i; }
  else if (i < 1048576){ src = wq; dst = wqb; off = i -  524288; }
  else if (i < 1572864){ src = wk; dst = wkb; off = i - 1048576; }
  else if (i < 1835008){ src = wv; dst = wvb; off = i - 1572864; }
  else                 { src = wo; dst = wob; off = i - 1835008; }
  float4 v = ((const float4*)src)[off];
  uint2 r;
  r.x = (u32)f2b(v.x) | ((u32)f2b(v.y) << 16);
  r.y = (u32)f2b(v.z) | ((u32)f2b(v.w) << 16);
  ((uint2*)dst)[off] = r;
}

// ---------------- bt-GEMM core: C[M,N] = A[M,K]*B[N,K]^T, 128x128 tile, BK=64 ----------------
__device__ __forceinline__ void gemm_core(const u16* __restrict__ A, const u16* __restrict__ B,
                                          void* __restrict__ C, int N, int K,
                                          int m0, int n0, int outbf, u16* At, u16* Bt){
  const int tid = threadIdx.x;
  const int l = tid & 63, w = tid >> 6;
  const int wrow = (w >> 1) * 64, wcol = (w & 1) * 64;
  f4v acc[4][4];
  #pragma unroll
  for (int a = 0; a < 4; a++)
    #pragma unroll
    for (int b = 0; b < 4; b++) acc[a][b] = (f4v)0.0f;

  const int crow = l >> 3;
  const int ksrc = ((l & 7) ^ crow) * 8;

  for (int k0 = 0; k0 < K; k0 += 64){
    const u16* Abase = A + (size_t)m0 * K + k0;
    const u16* Bbase = B + (size_t)n0 * K + k0;
    #pragma unroll
    for (int c = 0; c < 4; c++){
      int chunk = w * 4 + c;
      int row = chunk * 8 + crow;
      __builtin_amdgcn_global_load_lds((const AS1 void*)(Abase + (size_t)row * K + ksrc),
                                       (AS3 void*)(At + chunk * 512), 16, 0, 0);
      __builtin_amdgcn_global_load_lds((const AS1 void*)(Bbase + (size_t)row * K + ksrc),
                                       (AS3 void*)(Bt + chunk * 512), 16, 0, 0);
    }
    __syncthreads();
    #pragma unroll
    for (int kk = 0; kk < 2; kk++){
      bf8v af[4], bfr[4];
      #pragma unroll
      for (int mr = 0; mr < 4; mr++){
        int row = wrow + mr * 16 + (l & 15);
        af[mr] = *(const bf8v*)(At + row * 64 + (((kk * 32 + (l >> 4) * 8)) ^ ((row & 7) * 8)));
      }
      #pragma unroll
      for (int nc = 0; nc < 4; nc++){
        int row = wcol + nc * 16 + (l & 15);
        bfr[nc] = *(const bf8v*)(Bt + row * 64 + (((kk * 32 + (l >> 4) * 8)) ^ ((row & 7) * 8)));
      }
      #pragma unroll
      for (int mr = 0; mr < 4; mr++)
        #pragma unroll
        for (int nc = 0; nc < 4; nc++)
          acc[mr][nc] = __builtin_amdgcn_mfma_f32_16x16x32_bf16(af[mr], bfr[nc], acc[mr][nc], 0, 0, 0);
    }
    __syncthreads();
  }
  #pragma unroll
  for (int mr = 0; mr < 4; mr++)
    #pragma unroll
    for (int nc = 0; nc < 4; nc++)
      #pragma unroll
      for (int rr = 0; rr < 4; rr++){
        int row = m0 + wrow + mr * 16 + (l >> 4) * 4 + rr;
        int col = n0 + wcol + nc * 16 + (l & 15);
        if (outbf) ((u16*)C)[(size_t)row * N + col] = f2b(acc[mr][nc][rr]);
        else       ((float*)C)[(size_t)row * N + col] = acc[mr][nc][rr];
      }
}

__global__ __launch_bounds__(256) void qkv_gemm(const u16* __restrict__ xb,
                                                const u16* __restrict__ wqb, const u16* __restrict__ wkb,
                                                const u16* __restrict__ wvb,
                                                float* qf, float* kf, u16* vbb){
  __shared__ u16 At[8192], Bt[8192];
  int b = (blockIdx.x & 7) * 80 + (blockIdx.x >> 3);   // bijective XCD swizzle (640 = 8*80)
  const u16* Bp; void* Cp; int N, sh, outbf;
  if (b < 256)      { Bp = wqb; Cp = qf;  N = 2048; sh = 4; outbf = 0; }
  else if (b < 512) { Bp = wkb; Cp = kf;  N = 2048; sh = 4; outbf = 0; b -= 256; }
  else              { Bp = wvb; Cp = vbb; N = 1024; sh = 3; outbf = 1; b -= 512; }
  int m0 = (b >> sh) * 128, n0 = (b & ((1 << sh) - 1)) * 128;
  gemm_core(xb, Bp, Cp, N, 1024, m0, n0, outbf, At, Bt);
}

__global__ __launch_bounds__(256) void o_gemm(const u16* __restrict__ yb, const u16* __restrict__ wob,
                                              float* out){
  __shared__ u16 At[8192], Bt[8192];
  int b = (blockIdx.x & 7) * 16 + (blockIdx.x >> 3);   // 128 = 8*16
  gemm_core(yb, wob, out, 1024, 1024, (b >> 3) * 128, (b & 7) * 128, 0, At, Bt);
}

// ---------------- merged ReLU + top-32-of-128 ----------------
__global__ __launch_bounds__(256) void topk2(const float* __restrict__ qf, const float* __restrict__ kf,
                                             u16* __restrict__ qsb, u16* __restrict__ ksb){
  int w = threadIdx.x >> 6, l = threadIdx.x & 63;
  int b = blockIdx.x;
  const float* src; u16* dst;
  if (b < 8192){ src = qf; dst = qsb; } else { src = kf; dst = ksb; b -= 8192; }
  int row = b * 4 + w;
  int t = row >> 4, h = row & 15;
  const float* sp = src + (size_t)t * 2048 + h * 128 + l * 2;
  float v0 = sp[0], v1 = sp[1];
  v0 = v0 > 0.f ? v0 : 0.f;
  v1 = v1 > 0.f ? v1 : 0.f;
  u32 u0 = __builtin_bit_cast(u32, v0), u1 = __builtin_bit_cast(u32, v1);
  u32 pre = 0;
  for (int bb = 30; bb >= 0; --bb){
    u32 cand = pre | (1u << bb);
    int c = __builtin_popcountll(__ballot(u0 >= cand)) + __builtin_popcountll(__ballot(u1 >= cand));
    if (c >= 32) pre = cand;
  }
  u16 o0 = (u0 >= pre) ? f2b(v0) : (u16)0;
  u16 o1 = (u1 >= pre) ? f2b(v1) : (u16)0;
  ((u32*)(dst + ((size_t)h * 2048 + t) * 128))[l] = (u32)o0 | ((u32)o1 << 16);
}

// ---------------- V transpose: vbb [T][H*64] -> vtb [H][64][T] ----------------
__global__ __launch_bounds__(256) void vtk(const u16* __restrict__ vbb, u16* __restrict__ vtb){
  __shared__ u16 Lt[64][72];
  int h = blockIdx.x >> 5, tt = blockIdx.x & 31;
  int tid = threadIdx.x;
  #pragma unroll
  for (int i = 0; i < 2; i++){
    int s = i * 256 + tid, j = s >> 3, c8 = s & 7;
    *(int4*)&Lt[j][c8 * 8] = *(const int4*)(vbb + (size_t)(tt * 64 + j) * 1024 + h * 64 + c8 * 8);
  }
  __syncthreads();
  #pragma unroll
  for (int i = 0; i < 2; i++){
    int s = i * 256 + tid, d = s >> 3, jc = s & 7;
    union { int4 v; u16 u[8]; } tmp;
    #pragma unroll
    for (int e = 0; e < 8; e++) tmp.u[e] = Lt[jc * 8 + e][d];
    *(int4*)(vtb + ((size_t)h * 64 + d) * 2048 + tt * 64 + jc * 8) = tmp.v;
  }
}

// ---------------- chunk-parallel causal p=1 attention (8 waves, dbuf, gload_lds) ----------------
// grid: 640 blocks = 8 XCD x 80 slots; h pinned per XCD. QBLK=128, KVBLK=64, chunk=8 tiles.
__global__ __launch_bounds__(512) void attn3(const u16* __restrict__ qs, const u16* __restrict__ ks,
                                             const u16* __restrict__ vt, const float* __restrict__ sink,
                                             const float* __restrict__ logbeta, u16* __restrict__ yout,
                                             float* __restrict__ Yp, float* __restrict__ Dp){
  __shared__ u16 Kt[2][8192];     // [buf][64 rows x 128] chunk-swizzled
  __shared__ u16 Vt[2][4096];     // [buf][64 d x 64 j]  chunk-swizzled
  __shared__ u16 St[8][16 * 72];  // per-wave [16 rows][72] (144B stride)
  const int tid = threadIdx.x, l = tid & 63, w = tid >> 6;
  const int b = blockIdx.x;
  const int slot = b >> 3;
  const int h = (b & 7) + 8 * (slot / 40);
  const int u = slot % 40;
  int it, chunk, nch;
  if (u < 4)       { it = u; chunk = 0; nch = 1; }
  else if (u < 12) { it = 4 + ((u - 4) >> 1);  chunk = (u - 4) & 1;  nch = 2; }
  else if (u < 24) { it = 8 + (u - 12) / 3;    chunk = (u - 12) % 3; nch = 3; }
  else             { it = 12 + ((u - 24) >> 2); chunk = (u - 24) & 3; nch = 4; }
  const int jt0 = chunk * 8;
  const int jt1 = min(jt0 + 8, 2 * it + 2);    // exclusive; jtmax = 2*it+1
  const int qrow0 = it * 128 + w * 16;
  const float beta = expf(logbeta[0]);

  bf8v qfr[4];
  {
    int trow = qrow0 + (l & 15);
    const u16* qrow = qs + ((size_t)h * 2048 + trow) * 128 + (l >> 4) * 8;
    #pragma unroll
    for (int kk = 0; kk < 4; kk++) qfr[kk] = *(const bf8v*)(qrow + kk * 32);
  }

  f4v accY[4];
  #pragma unroll
  for (int c = 0; c < 4; c++) accY[c] = (f4v)0.0f;
  float dsum[4] = {0.f, 0.f, 0.f, 0.f};

  const u16* kroot = ks + (size_t)h * 2048 * 128;
  const u16* vroot = vt + (size_t)h * 64 * 2048;

  auto stage = [&](int jt, int buf){
    const u16* kbase = kroot + (size_t)jt * 64 * 128;
    #pragma unroll
    for (int i = 0; i < 2; i++){
      int g = i * 512 + tid;
      int r = g >> 4, c = g & 15;
      __builtin_amdgcn_global_load_lds((const AS1 void*)(kbase + r * 128 + (c ^ (r & 7)) * 8),
                                       (AS3 void*)(&Kt[buf][(i * 512 + w * 64) * 8]), 16, 0, 0);
    }
    {
      int d = tid >> 3, c = tid & 7;
      __builtin_amdgcn_global_load_lds((const AS1 void*)(vroot + (size_t)d * 2048 + jt * 64 + (c ^ (d & 7)) * 8),
                                       (AS3 void*)(&Vt[buf][w * 512]), 16, 0, 0);
    }
  };

  stage(jt0, 0);
  __syncthreads();
  int buf = 0;
  for (int jt = jt0; jt < jt1; ++jt){
    if (jt + 1 < jt1) stage(jt + 1, buf ^ 1);

    if (jt * 64 <= qrow0 + 15){        // not fully above diagonal for this wave
      f4v accS[4];
      #pragma unroll
      for (int c = 0; c < 4; c++) accS[c] = (f4v)0.0f;
      #pragma unroll
      for (int c = 0; c < 4; c++){
        int r = c * 16 + (l & 15);
        #pragma unroll
        for (int kk = 0; kk < 4; kk++){
          int ch = kk * 4 + (l >> 4);
          bf8v kfr = *(const bf8v*)(&Kt[buf][r * 128 + ((ch ^ (r & 7)) * 8)]);
          accS[c] = __builtin_amdgcn_mfma_f32_16x16x32_bf16(qfr[kk], kfr, accS[c], 0, 0, 0);
        }
      }
      if (jt * 64 + 63 > qrow0){       // diagonal: elementwise causal mask
        #pragma unroll
        for (int c = 0; c < 4; c++)
          #pragma unroll
          for (int rr = 0; rr < 4; rr++){
            int i = qrow0 + (l >> 4) * 4 + rr;
            int j = jt * 64 + c * 16 + (l & 15);
            if (j > i) accS[c][rr] = 0.f;
          }
      }
      #pragma unroll
      for (int c = 0; c < 4; c++)
        #pragma unroll
        for (int rr = 0; rr < 4; rr++){
          dsum[rr] += accS[c][rr];
          St[w][((l >> 4) * 4 + rr) * 72 + c * 16 + (l & 15)] = f2b(accS[c][rr]);
        }
      // PV (wave-private St -> compiler lgkmcnt only)
      #pragma unroll
      for (int k2 = 0; k2 < 2; k2++){
        bf8v afr = *(const bf8v*)(&St[w][(l & 15) * 72 + k2 * 32 + (l >> 4) * 8]);
        #pragma unroll
        for (int c = 0; c < 4; c++){
          int d = c * 16 + (l & 15);
          int ch = k2 * 4 + (l >> 4);
          bf8v vfr = *(const bf8v*)(&Vt[buf][d * 64 + ((ch ^ (d & 7)) * 8)]);
          accY[c] = __builtin_amdgcn_mfma_f32_16x16x32_bf16(afr, vfr, accY[c], 0, 0, 0);
        }
      }
    }
    __syncthreads();   // all waves done with buf; next tile's loads landed
    buf ^= 1;
  }

  #pragma unroll
  for (int rr = 0; rr < 4; rr++){
    float s = dsum[rr];
    s += __shfl_xor(s, 1, 64);
    s += __shfl_xor(s, 2, 64);
    s += __shfl_xor(s, 4, 64);
    s += __shfl_xor(s, 8, 64);
    dsum[rr] = s;
  }

  if (nch == 1){
    #pragma unroll
    for (int c = 0; c < 4; c++){
      float sv = sink[h * 64 + c * 16 + (l & 15)];
      #pragma unroll
      for (int rr = 0; rr < 4; rr++){
        float den = dsum[rr] + beta;
        float inv = 1.0f / fmaxf(den, 1e-12f);
        float y = (accY[c][rr] + beta * sv) * inv;
        int row = qrow0 + (l >> 4) * 4 + rr;
        yout[(size_t)row * 1024 + h * 64 + c * 16 + (l & 15)] = f2b(y);
      }
    }
  } else {
    float* yp = Yp + ((size_t)h * 40 + u) * 8192;
    #pragma unroll
    for (int c = 0; c < 4; c++)
      #pragma unroll
      for (int rr = 0; rr < 4; rr++){
        int rowib = w * 16 + (l >> 4) * 4 + rr;
        yp[rowib * 64 + c * 16 + (l & 15)] = accY[c][rr];
      }
    if ((l & 15) == 0){
      #pragma unroll
      for (int rr = 0; rr < 4; rr++)
        Dp[((size_t)h * 40 + u) * 128 + w * 16 + (l >> 4) * 4 + rr] = dsum[rr];
    }
  }
}

// combine partials for it 4..15 (grid 16 x 12)
__global__ __launch_bounds__(256) void attn_reduce(const float* __restrict__ Yp, const float* __restrict__ Dp,
                                                   const float* __restrict__ sink, const float* __restrict__ logbeta,
                                                   u16* __restrict__ yout){
  int blk = blockIdx.x;
  int h = blk / 12, it = 4 + blk % 12;
  int nch = it / 4 + 1;
  int u0 = (it < 8) ? 4 + (it - 4) * 2 : (it < 12) ? 12 + (it - 8) * 3 : 24 + (it - 12) * 4;
  float beta = expf(logbeta[0]);
  __shared__ float inv_s[128];
  int t = threadIdx.x;
  if (t < 128){
    float s = 0.f;
    for (int c = 0; c < nch; c++) s += Dp[((size_t)h * 40 + u0 + c) * 128 + t];
    inv_s[t] = 1.0f / fmaxf(s + beta, 1e-12f);
  }
  __syncthreads();
  const float* base = Yp + ((size_t)h * 40 + u0) * 8192;
  #pragma unroll
  for (int e = 0; e < 32; e++){
    int idx = e * 256 + t;
    float acc = 0.f;
    for (int c = 0; c < nch; c++) acc += base[c * 8192 + idx];
    int row = idx >> 6, col = idx & 63;
    float y = (acc + beta * sink[h * 64 + col]) * inv_s[row];
    yout[(size_t)(it * 128 + row) * 1024 + h * 64 + col] = f2b(y);
  }
}

extern "C" void kernel_launch(void* const* d_in, const int* in_sizes, int n_in,
                              void* d_out, int out_size, void* d_ws, size_t ws_size,
                              hipStream_t stream){
  const float* x    = (const float*)d_in[0];
  const float* Wq   = (const float*)d_in[1];
  const float* Wk   = (const float*)d_in[2];
  const float* Wv   = (const float*)d_in[3];
  const float* Wo   = (const float*)d_in[4];
  const float* sink = (const float*)d_in[5];
  const float* logb = (const float*)d_in[6];

  char* ws = (char*)d_ws;
  u16*   xb  = (u16*)(ws + 0);            // 4 MB
  u16*   wqb = (u16*)(ws + 4194304);      // 4 MB
  u16*   wkb = (u16*)(ws + 8388608);      // 4 MB
  u16*   wvb = (u16*)(ws + 12582912);     // 2 MB
  u16*   wob = (u16*)(ws + 14680064);     // 2 MB
  float* qf  = (float*)(ws + 16777216);   // 16 MB (dead after topk2)
  float* kf  = (float*)(ws + 33554432);   // 16 MB (dead after topk2)
  u16*   qsb = (u16*)(ws + 50331648);     // 8 MB  [16][2048][128]
  u16*   ksb = (u16*)(ws + 58720256);     // 8 MB
  u16*   vbb = (u16*)(ws + 67108864);     // 4 MB  [2048][1024]
  u16*   yb  = (u16*)(ws + 71303168);     // 4 MB  [2048][1024]
  float* Yp  = (float*)(ws + 16777216);   // 21 MB partials (over dead qf + start of kf)
  float* Dp  = (float*)(ws + 37748736);   // 320 KB (inside dead kf)
  u16*   vtb = (u16*)(ws + 41943040);     // 4 MB  V^T [16][64][2048] (inside dead kf tail)

  conv_all<<<8192, 256, 0, stream>>>(x, Wq, Wk, Wv, Wo, xb, wqb, wkb, wvb, wob);
  qkv_gemm<<<640, 256, 0, stream>>>(xb, wqb, wkb, wvb, qf, kf, vbb);
  topk2<<<16384, 256, 0, stream>>>(qf, kf, qsb, ksb);
  vtk<<<512, 256, 0, stream>>>(vbb, vtb);
  attn3<<<640, 512, 0, stream>>>(qsb, ksb, vtb, sink, logb, yb, Yp, Dp);
  attn_reduce<<<192, 256, 0, stream>>>(Yp, Dp, sink, logb, yb);
  o_gemm<<<128, 256, 0, stream>>>(yb, wob, (float*)d_out);
}

// Round 5
// 151.471 us; speedup vs baseline: 1.5710x; 1.1675x over previous
//
#include <hip/hip_runtime.h>

typedef __attribute__((ext_vector_type(8))) short bf8v;   // 8 bf16 (4 VGPRs)
typedef __attribute__((ext_vector_type(4))) float f4v;    // MFMA acc
typedef unsigned short u16;
typedef unsigned int   u32;
#define AS1 __attribute__((address_space(1)))
#define AS3 __attribute__((address_space(3)))

__device__ inline u16 f2b(float f){
  u32 u = __builtin_bit_cast(u32, f);
  u += 0x7fffu + ((u >> 16) & 1u);     // RNE
  return (u16)(u >> 16);
}

// ---------------- merged f32 -> bf16 conversion (x, Wq, Wk, Wv, Wo) ----------------
__global__ __launch_bounds__(256) void conv_all(const float* __restrict__ x,  const float* __restrict__ wq,
                                                const float* __restrict__ wk, const float* __restrict__ wv,
                                                const float* __restrict__ wo,
                                                u16* xb, u16* wqb, u16* wkb, u16* wvb, u16* wob){
  int i = blockIdx.x * 256 + threadIdx.x;
  const float* src; u16* dst; int off;
  if      (i <  524288){ src = x;  dst = xb;  off = i; }
  else if (i < 1048576){ src = wq; dst = wqb; off = i -  524288; }
  else if (i < 1572864){ src = wk; dst = wkb; off = i - 1048576; }
  else if (i < 1835008){ src = wv; dst = wvb; off = i - 1572864; }
  else                 { src = wo; dst = wob; off = i - 1835008; }
  float4 v = ((const float4*)src)[off];
  uint2 r;
  r.x = (u32)f2b(v.x) | ((u32)f2b(v.y) << 16);
  r.y = (u32)f2b(v.z) | ((u32)f2b(v.w) << 16);
  ((uint2*)dst)[off] = r;
}

// ---------------- bt-GEMM core: acc = A[M,K tile m0] * B[N,K tile n0]^T ----------------
// 128x128 tile, BK=64, prefetch double-buffer (stage k+1 BEFORE compute k), gload_lds w16,
// XOR-chunk swizzle (linear LDS dest + inverse-swizzled global source + swizzled read).
__device__ __forceinline__ void gemm_core(const u16* __restrict__ A, const u16* __restrict__ B,
                                          int K, int m0, int n0, u16* lds, f4v acc[4][4]){
  const int tid = threadIdx.x;
  const int l = tid & 63, w = tid >> 6;
  const int wrow = (w >> 1) * 64, wcol = (w & 1) * 64;
  #pragma unroll
  for (int a = 0; a < 4; a++)
    #pragma unroll
    for (int b = 0; b < 4; b++) acc[a][b] = (f4v)0.0f;

  const int crow = l >> 3;
  const int ksrc = ((l & 7) ^ crow) * 8;

  auto stage = [&](int k0, int buf){
    const u16* Abase = A + (size_t)m0 * K + k0;
    const u16* Bbase = B + (size_t)n0 * K + k0;
    u16* At = lds + buf * 16384;
    u16* Bt = At + 8192;
    #pragma unroll
    for (int c = 0; c < 4; c++){
      int chunk = w * 4 + c;
      int row = chunk * 8 + crow;
      __builtin_amdgcn_global_load_lds((const AS1 void*)(Abase + (size_t)row * K + ksrc),
                                       (AS3 void*)(At + chunk * 512), 16, 0, 0);
      __builtin_amdgcn_global_load_lds((const AS1 void*)(Bbase + (size_t)row * K + ksrc),
                                       (AS3 void*)(Bt + chunk * 512), 16, 0, 0);
    }
  };

  stage(0, 0);
  __syncthreads();
  int buf = 0;
  for (int k0 = 0; k0 < K; k0 += 64){
    if (k0 + 64 < K) stage(k0 + 64, buf ^ 1);   // prefetch overlaps this step's compute
    const u16* At = lds + buf * 16384;
    const u16* Bt = At + 8192;
    #pragma unroll
    for (int kk = 0; kk < 2; kk++){
      bf8v af[4], bfr[4];
      #pragma unroll
      for (int mr = 0; mr < 4; mr++){
        int row = wrow + mr * 16 + (l & 15);
        af[mr] = *(const bf8v*)(At + row * 64 + (((kk * 32 + (l >> 4) * 8)) ^ ((row & 7) * 8)));
      }
      #pragma unroll
      for (int nc = 0; nc < 4; nc++){
        int row = wcol + nc * 16 + (l & 15);
        bfr[nc] = *(const bf8v*)(Bt + row * 64 + (((kk * 32 + (l >> 4) * 8)) ^ ((row & 7) * 8)));
      }
      #pragma unroll
      for (int mr = 0; mr < 4; mr++)
        #pragma unroll
        for (int nc = 0; nc < 4; nc++)
          acc[mr][nc] = __builtin_amdgcn_mfma_f32_16x16x32_bf16(af[mr], bfr[nc], acc[mr][nc], 0, 0, 0);
    }
    __syncthreads();   // drains prefetch (compute phase was in flight) + read/write hazard
    buf ^= 1;
  }
}

// Q/K -> f32 scores; V -> transposed bf16 [h][d][t] directly (vtk fused away)
__global__ __launch_bounds__(256) void qkv_gemm(const u16* __restrict__ xb,
                                                const u16* __restrict__ wqb, const u16* __restrict__ wkb,
                                                const u16* __restrict__ wvb,
                                                float* qf, float* kf, u16* vtb){
  __shared__ u16 lds[32768];   // 64 KB: 2 x (At 16KB + Bt 16KB)
  int b = (blockIdx.x & 7) * 80 + (blockIdx.x >> 3);   // bijective XCD swizzle (640 = 8*80)
  const u16* Bp; int which;    // 0=Q 1=K 2=V
  if (b < 256)      { Bp = wqb; which = 0; }
  else if (b < 512) { Bp = wkb; which = 1; b -= 256; }
  else              { Bp = wvb; which = 2; b -= 512; }
  int sh = (which == 2) ? 3 : 4;
  int m0 = (b >> sh) * 128, n0 = (b & ((1 << sh) - 1)) * 128;

  f4v acc[4][4];
  gemm_core(xb, Bp, 1024, m0, n0, lds, acc);

  const int l = threadIdx.x & 63, w = threadIdx.x >> 6;
  const int wrow = (w >> 1) * 64, wcol = (w & 1) * 64;
  if (which < 2){
    float* C = which ? kf : qf;
    #pragma unroll
    for (int mr = 0; mr < 4; mr++)
      #pragma unroll
      for (int nc = 0; nc < 4; nc++)
        #pragma unroll
        for (int rr = 0; rr < 4; rr++){
          int row = m0 + wrow + mr * 16 + (l >> 4) * 4 + rr;
          int col = n0 + wcol + nc * 16 + (l & 15);
          C[(size_t)row * 2048 + col] = acc[mr][nc][rr];
        }
  } else {
    // transposed store: vtb[h][d][t], 4 consecutive t packed per uint2
    #pragma unroll
    for (int mr = 0; mr < 4; mr++)
      #pragma unroll
      for (int nc = 0; nc < 4; nc++){
        int gcol = n0 + wcol + nc * 16 + (l & 15);
        int t0 = m0 + wrow + mr * 16 + (l >> 4) * 4;
        uint2 pk;
        pk.x = (u32)f2b(acc[mr][nc][0]) | ((u32)f2b(acc[mr][nc][1]) << 16);
        pk.y = (u32)f2b(acc[mr][nc][2]) | ((u32)f2b(acc[mr][nc][3]) << 16);
        *(uint2*)(vtb + (size_t)gcol * 2048 + t0) = pk;   // gcol = h*64+d
      }
  }
}

__global__ __launch_bounds__(256) void o_gemm(const u16* __restrict__ yb, const u16* __restrict__ wob,
                                              float* out){
  __shared__ u16 lds[32768];
  int b = (blockIdx.x & 7) * 16 + (blockIdx.x >> 3);   // 128 = 8*16
  int m0 = (b >> 3) * 128, n0 = (b & 7) * 128;
  f4v acc[4][4];
  gemm_core(yb, wob, 1024, m0, n0, lds, acc);
  const int l = threadIdx.x & 63, w = threadIdx.x >> 6;
  const int wrow = (w >> 1) * 64, wcol = (w & 1) * 64;
  #pragma unroll
  for (int mr = 0; mr < 4; mr++)
    #pragma unroll
    for (int nc = 0; nc < 4; nc++)
      #pragma unroll
      for (int rr = 0; rr < 4; rr++){
        int row = m0 + wrow + mr * 16 + (l >> 4) * 4 + rr;
        int col = n0 + wcol + nc * 16 + (l & 15);
        out[(size_t)row * 1024 + col] = acc[mr][nc][rr];
      }
}

// ---------------- merged ReLU + top-32-of-128 ----------------
__global__ __launch_bounds__(256) void topk2(const float* __restrict__ qf, const float* __restrict__ kf,
                                             u16* __restrict__ qsb, u16* __restrict__ ksb){
  int w = threadIdx.x >> 6, l = threadIdx.x & 63;
  int b = blockIdx.x;
  const float* src; u16* dst;
  if (b < 8192){ src = qf; dst = qsb; } else { src = kf; dst = ksb; b -= 8192; }
  int row = b * 4 + w;
  int t = row >> 4, h = row & 15;
  const float* sp = src + (size_t)t * 2048 + h * 128 + l * 2;
  float v0 = sp[0], v1 = sp[1];
  v0 = v0 > 0.f ? v0 : 0.f;
  v1 = v1 > 0.f ? v1 : 0.f;
  u32 u0 = __builtin_bit_cast(u32, v0), u1 = __builtin_bit_cast(u32, v1);
  u32 pre = 0;
  for (int bb = 30; bb >= 0; --bb){
    u32 cand = pre | (1u << bb);
    int c = __builtin_popcountll(__ballot(u0 >= cand)) + __builtin_popcountll(__ballot(u1 >= cand));
    if (c >= 32) pre = cand;
  }
  u16 o0 = (u0 >= pre) ? f2b(v0) : (u16)0;
  u16 o1 = (u1 >= pre) ? f2b(v1) : (u16)0;
  ((u32*)(dst + ((size_t)h * 2048 + t) * 128))[l] = (u32)o0 | ((u32)o1 << 16);
}

// ---------------- chunk-parallel causal p=1 attention (8 waves, dbuf, gload_lds) ----------------
__global__ __launch_bounds__(512) void attn3(const u16* __restrict__ qs, const u16* __restrict__ ks,
                                             const u16* __restrict__ vt, const float* __restrict__ sink,
                                             const float* __restrict__ logbeta, u16* __restrict__ yout,
                                             float* __restrict__ Yp, float* __restrict__ Dp){
  __shared__ u16 Kt[2][8192];
  __shared__ u16 Vt[2][4096];
  __shared__ u16 St[8][16 * 72];
  const int tid = threadIdx.x, l = tid & 63, w = tid >> 6;
  const int b = blockIdx.x;
  const int slot = b >> 3;
  const int h = (b & 7) + 8 * (slot / 40);
  const int u = slot % 40;
  int it, chunk, nch;
  if (u < 4)       { it = u; chunk = 0; nch = 1; }
  else if (u < 12) { it = 4 + ((u - 4) >> 1);  chunk = (u - 4) & 1;  nch = 2; }
  else if (u < 24) { it = 8 + (u - 12) / 3;    chunk = (u - 12) % 3; nch = 3; }
  else             { it = 12 + ((u - 24) >> 2); chunk = (u - 24) & 3; nch = 4; }
  const int jt0 = chunk * 8;
  const int jt1 = min(jt0 + 8, 2 * it + 2);
  const int qrow0 = it * 128 + w * 16;
  const float beta = expf(logbeta[0]);

  bf8v qfr[4];
  {
    int trow = qrow0 + (l & 15);
    const u16* qrow = qs + ((size_t)h * 2048 + trow) * 128 + (l >> 4) * 8;
    #pragma unroll
    for (int kk = 0; kk < 4; kk++) qfr[kk] = *(const bf8v*)(qrow + kk * 32);
  }

  f4v accY[4];
  #pragma unroll
  for (int c = 0; c < 4; c++) accY[c] = (f4v)0.0f;
  float dsum[4] = {0.f, 0.f, 0.f, 0.f};

  const u16* kroot = ks + (size_t)h * 2048 * 128;
  const u16* vroot = vt + (size_t)h * 64 * 2048;

  auto stage = [&](int jt, int buf){
    const u16* kbase = kroot + (size_t)jt * 64 * 128;
    #pragma unroll
    for (int i = 0; i < 2; i++){
      int g = i * 512 + tid;
      int r = g >> 4, c = g & 15;
      __builtin_amdgcn_global_load_lds((const AS1 void*)(kbase + r * 128 + (c ^ (r & 7)) * 8),
                                       (AS3 void*)(&Kt[buf][(i * 512 + w * 64) * 8]), 16, 0, 0);
    }
    {
      int d = tid >> 3, c = tid & 7;
      __builtin_amdgcn_global_load_lds((const AS1 void*)(vroot + (size_t)d * 2048 + jt * 64 + (c ^ (d & 7)) * 8),
                                       (AS3 void*)(&Vt[buf][w * 512]), 16, 0, 0);
    }
  };

  stage(jt0, 0);
  __syncthreads();
  int buf = 0;
  for (int jt = jt0; jt < jt1; ++jt){
    if (jt + 1 < jt1) stage(jt + 1, buf ^ 1);

    if (jt * 64 <= qrow0 + 15){
      f4v accS[4];
      #pragma unroll
      for (int c = 0; c < 4; c++) accS[c] = (f4v)0.0f;
      __builtin_amdgcn_s_setprio(1);
      #pragma unroll
      for (int c = 0; c < 4; c++){
        int r = c * 16 + (l & 15);
        #pragma unroll
        for (int kk = 0; kk < 4; kk++){
          int ch = kk * 4 + (l >> 4);
          bf8v kfr = *(const bf8v*)(&Kt[buf][r * 128 + ((ch ^ (r & 7)) * 8)]);
          accS[c] = __builtin_amdgcn_mfma_f32_16x16x32_bf16(qfr[kk], kfr, accS[c], 0, 0, 0);
        }
      }
      __builtin_amdgcn_s_setprio(0);
      if (jt * 64 + 63 > qrow0){
        #pragma unroll
        for (int c = 0; c < 4; c++)
          #pragma unroll
          for (int rr = 0; rr < 4; rr++){
            int i = qrow0 + (l >> 4) * 4 + rr;
            int j = jt * 64 + c * 16 + (l & 15);
            if (j > i) accS[c][rr] = 0.f;
          }
      }
      #pragma unroll
      for (int c = 0; c < 4; c++)
        #pragma unroll
        for (int rr = 0; rr < 4; rr++){
          dsum[rr] += accS[c][rr];
          St[w][((l >> 4) * 4 + rr) * 72 + c * 16 + (l & 15)] = f2b(accS[c][rr]);
        }
      __builtin_amdgcn_s_setprio(1);
      #pragma unroll
      for (int k2 = 0; k2 < 2; k2++){
        bf8v afr = *(const bf8v*)(&St[w][(l & 15) * 72 + k2 * 32 + (l >> 4) * 8]);
        #pragma unroll
        for (int c = 0; c < 4; c++){
          int d = c * 16 + (l & 15);
          int ch = k2 * 4 + (l >> 4);
          bf8v vfr = *(const bf8v*)(&Vt[buf][d * 64 + ((ch ^ (d & 7)) * 8)]);
          accY[c] = __builtin_amdgcn_mfma_f32_16x16x32_bf16(afr, vfr, accY[c], 0, 0, 0);
        }
      }
      __builtin_amdgcn_s_setprio(0);
    }
    __syncthreads();
    buf ^= 1;
  }

  #pragma unroll
  for (int rr = 0; rr < 4; rr++){
    float s = dsum[rr];
    s += __shfl_xor(s, 1, 64);
    s += __shfl_xor(s, 2, 64);
    s += __shfl_xor(s, 4, 64);
    s += __shfl_xor(s, 8, 64);
    dsum[rr] = s;
  }

  if (nch == 1){
    #pragma unroll
    for (int c = 0; c < 4; c++){
      float sv = sink[h * 64 + c * 16 + (l & 15)];
      #pragma unroll
      for (int rr = 0; rr < 4; rr++){
        float den = dsum[rr] + beta;
        float inv = 1.0f / fmaxf(den, 1e-12f);
        float y = (accY[c][rr] + beta * sv) * inv;
        int row = qrow0 + (l >> 4) * 4 + rr;
        yout[(size_t)row * 1024 + h * 64 + c * 16 + (l & 15)] = f2b(y);
      }
    }
  } else {
    float* yp = Yp + ((size_t)h * 40 + u) * 8192;
    #pragma unroll
    for (int c = 0; c < 4; c++)
      #pragma unroll
      for (int rr = 0; rr < 4; rr++){
        int rowib = w * 16 + (l >> 4) * 4 + rr;
        yp[rowib * 64 + c * 16 + (l & 15)] = accY[c][rr];
      }
    if ((l & 15) == 0){
      #pragma unroll
      for (int rr = 0; rr < 4; rr++)
        Dp[((size_t)h * 40 + u) * 128 + w * 16 + (l >> 4) * 4 + rr] = dsum[rr];
    }
  }
}

// combine partials for it 4..15 (grid 16 x 12)
__global__ __launch_bounds__(256) void attn_reduce(const float* __restrict__ Yp, const float* __restrict__ Dp,
                                                   const float* __restrict__ sink, const float* __restrict__ logbeta,
                                                   u16* __restrict__ yout){
  int blk = blockIdx.x;
  int h = blk / 12, it = 4 + blk % 12;
  int nch = it / 4 + 1;
  int u0 = (it < 8) ? 4 + (it - 4) * 2 : (it < 12) ? 12 + (it - 8) * 3 : 24 + (it - 12) * 4;
  float beta = expf(logbeta[0]);
  __shared__ float inv_s[128];
  int t = threadIdx.x;
  if (t < 128){
    float s = 0.f;
    for (int c = 0; c < nch; c++) s += Dp[((size_t)h * 40 + u0 + c) * 128 + t];
    inv_s[t] = 1.0f / fmaxf(s + beta, 1e-12f);
  }
  __syncthreads();
  const float* base = Yp + ((size_t)h * 40 + u0) * 8192;
  #pragma unroll
  for (int e = 0; e < 32; e++){
    int idx = e * 256 + t;
    float acc = 0.f;
    for (int c = 0; c < nch; c++) acc += base[c * 8192 + idx];
    int row = idx >> 6, col = idx & 63;
    float y = (acc + beta * sink[h * 64 + col]) * inv_s[row];
    yout[(size_t)(it * 128 + row) * 1024 + h * 64 + col] = f2b(y);
  }
}

extern "C" void kernel_launch(void* const* d_in, const int* in_sizes, int n_in,
                              void* d_out, int out_size, void* d_ws, size_t ws_size,
                              hipStream_t stream){
  const float* x    = (const float*)d_in[0];
  const float* Wq   = (const float*)d_in[1];
  const float* Wk   = (const float*)d_in[2];
  const float* Wv   = (const float*)d_in[3];
  const float* Wo   = (const float*)d_in[4];
  const float* sink = (const float*)d_in[5];
  const float* logb = (const float*)d_in[6];

  char* ws = (char*)d_ws;
  u16*   xb  = (u16*)(ws + 0);            // 4 MB
  u16*   wqb = (u16*)(ws + 4194304);      // 4 MB
  u16*   wkb = (u16*)(ws + 8388608);      // 4 MB
  u16*   wvb = (u16*)(ws + 12582912);     // 2 MB
  u16*   wob = (u16*)(ws + 14680064);     // 2 MB
  float* qf  = (float*)(ws + 16777216);   // 16 MB (live: qkv_gemm -> topk2)
  float* kf  = (float*)(ws + 33554432);   // 16 MB (live: qkv_gemm -> topk2)
  u16*   qsb = (u16*)(ws + 50331648);     // 8 MB  [16][2048][128]
  u16*   ksb = (u16*)(ws + 58720256);     // 8 MB
  u16*   vtb = (u16*)(ws + 67108864);     // 4 MB  V^T [16][64][2048] — OWN slot, no overlap with live kf
  u16*   yb  = (u16*)(ws + 71303168);     // 4 MB  [2048][1024]
  float* Yp  = (float*)(ws + 16777216);   // 21 MB partials (overlays qf+kf head AFTER topk2)
  float* Dp  = (float*)(ws + 37748736);   // 320 KB (inside dead kf, after topk2)

  conv_all<<<8192, 256, 0, stream>>>(x, Wq, Wk, Wv, Wo, xb, wqb, wkb, wvb, wob);
  qkv_gemm<<<640, 256, 0, stream>>>(xb, wqb, wkb, wvb, qf, kf, vtb);
  topk2<<<16384, 256, 0, stream>>>(qf, kf, qsb, ksb);
  attn3<<<640, 512, 0, stream>>>(qsb, ksb, vtb, sink, logb, yb, Yp, Dp);
  attn_reduce<<<192, 256, 0, stream>>>(Yp, Dp, sink, logb, yb);
  o_gemm<<<128, 256, 0, stream>>>(yb, wob, (float*)d_out);
}

// Round 6
// 145.078 us; speedup vs baseline: 1.6402x; 1.0441x over previous
//
#include <hip/hip_runtime.h>

typedef __attribute__((ext_vector_type(8))) short bf8v;   // 8 bf16 (4 VGPRs)
typedef __attribute__((ext_vector_type(4))) float f4v;    // MFMA acc
typedef unsigned short u16;
typedef unsigned int   u32;
#define AS1 __attribute__((address_space(1)))
#define AS3 __attribute__((address_space(3)))

__device__ inline u16 f2b(float f){
  u32 u = __builtin_bit_cast(u32, f);
  u += 0x7fffu + ((u >> 16) & 1u);     // RNE
  return (u16)(u >> 16);
}

// ---------------- merged f32 -> bf16 conversion (x, Wq, Wk, Wv, Wo) ----------------
__global__ __launch_bounds__(256) void conv_all(const float* __restrict__ x,  const float* __restrict__ wq,
                                                const float* __restrict__ wk, const float* __restrict__ wv,
                                                const float* __restrict__ wo,
                                                u16* xb, u16* wqb, u16* wkb, u16* wvb, u16* wob){
  int i = blockIdx.x * 256 + threadIdx.x;
  const float* src; u16* dst; int off;
  if      (i <  524288){ src = x;  dst = xb;  off = i; }
  else if (i < 1048576){ src = wq; dst = wqb; off = i -  524288; }
  else if (i < 1572864){ src = wk; dst = wkb; off = i - 1048576; }
  else if (i < 1835008){ src = wv; dst = wvb; off = i - 1572864; }
  else                 { src = wo; dst = wob; off = i - 1835008; }
  float4 v = ((const float4*)src)[off];
  uint2 r;
  r.x = (u32)f2b(v.x) | ((u32)f2b(v.y) << 16);
  r.y = (u32)f2b(v.z) | ((u32)f2b(v.w) << 16);
  ((uint2*)dst)[off] = r;
}

// ---------------- bt-GEMM core: acc = A[m0 tile] * B[n0 tile]^T, 128x128, BK=32 ----------------
// Deep pipeline: 5 LDS buffers (80KB), prefetch depth 3, counted vmcnt(12) (never 0 in main loop),
// raw s_barrier. gload_lds w16 linear dest + inverse-swizzled source (seg ^ (row>>1)&3) + swizzled read.
__device__ __forceinline__ void gemm_core(const u16* __restrict__ A, const u16* __restrict__ B,
                                          int K, int m0, int n0, u16* lds, f4v acc[4][4]){
  const int tid = threadIdx.x;
  const int l = tid & 63, w = tid >> 6;
  const int wrow = (w >> 1) * 64, wcol = (w & 1) * 64;
  #pragma unroll
  for (int a = 0; a < 4; a++)
    #pragma unroll
    for (int b = 0; b < 4; b++) acc[a][b] = (f4v)0.0f;

  // staging geometry: chunk c = 256*j + 64*w + l -> row=c>>2, seg=c&3, src seg = seg ^ ((row>>1)&3)
  const int c0 = w * 64 + l;
  const int c1 = c0 + 256;
  const int r0 = c0 >> 2, s0e = ((c0 & 3) ^ ((r0 >> 1) & 3)) * 8;
  const int r1 = c1 >> 2, s1e = ((c1 & 3) ^ ((r1 >> 1) & 3)) * 8;

  const u16* Aroot = A + (size_t)m0 * K;
  const u16* Broot = B + (size_t)n0 * K;

  auto stage = [&](int k0, int bb){   // bb = buffer base in elems
    const u16* Ab = Aroot + k0;
    const u16* Bb = Broot + k0;
    __builtin_amdgcn_global_load_lds((const AS1 void*)(Ab + (size_t)r0 * K + s0e),
                                     (AS3 void*)(lds + bb + w * 512), 16, 0, 0);
    __builtin_amdgcn_global_load_lds((const AS1 void*)(Ab + (size_t)r1 * K + s1e),
                                     (AS3 void*)(lds + bb + 2048 + w * 512), 16, 0, 0);
    __builtin_amdgcn_global_load_lds((const AS1 void*)(Bb + (size_t)r0 * K + s0e),
                                     (AS3 void*)(lds + bb + 4096 + w * 512), 16, 0, 0);
    __builtin_amdgcn_global_load_lds((const AS1 void*)(Bb + (size_t)r1 * K + s1e),
                                     (AS3 void*)(lds + bb + 6144 + w * 512), 16, 0, 0);
  };

  const int nst = K >> 5;
  stage(0, 0);
  stage(32, 8192);
  stage(64, 16384);

  const int kb = l >> 4;
  for (int i = 0; i < nst; ++i){
    int k3 = (i + 3) << 5;
    if (k3 < K) stage(k3, ((i + 3) % 5) * 8192);
    if      (i <  nst - 3) asm volatile("s_waitcnt vmcnt(12)" ::: "memory");
    else if (i == nst - 3) asm volatile("s_waitcnt vmcnt(8)"  ::: "memory");
    else if (i == nst - 2) asm volatile("s_waitcnt vmcnt(4)"  ::: "memory");
    else                   asm volatile("s_waitcnt vmcnt(0)"  ::: "memory");
    __builtin_amdgcn_sched_barrier(0);
    __builtin_amdgcn_s_barrier();

    const u16* At = lds + (i % 5) * 8192;
    const u16* Bt = At + 4096;
    bf8v af[4], bfr[4];
    #pragma unroll
    for (int mr = 0; mr < 4; mr++){
      int row = wrow + mr * 16 + (l & 15);
      af[mr] = *(const bf8v*)(At + row * 32 + ((kb ^ ((row >> 1) & 3)) * 8));
    }
    #pragma unroll
    for (int nc = 0; nc < 4; nc++){
      int row = wcol + nc * 16 + (l & 15);
      bfr[nc] = *(const bf8v*)(Bt + row * 32 + ((kb ^ ((row >> 1) & 3)) * 8));
    }
    __builtin_amdgcn_s_setprio(1);
    #pragma unroll
    for (int mr = 0; mr < 4; mr++)
      #pragma unroll
      for (int nc = 0; nc < 4; nc++)
        acc[mr][nc] = __builtin_amdgcn_mfma_f32_16x16x32_bf16(af[mr], bfr[nc], acc[mr][nc], 0, 0, 0);
    __builtin_amdgcn_s_setprio(0);
  }
}

// Q/K -> bf16 scores; V -> transposed bf16 [h][d][t] directly
__global__ __launch_bounds__(256) void qkv_gemm(const u16* __restrict__ xb,
                                                const u16* __restrict__ wqb, const u16* __restrict__ wkb,
                                                const u16* __restrict__ wvb,
                                                u16* qf, u16* kf, u16* vtb){
  __shared__ u16 lds[40960];   // 80 KB: 5 x (At 8KB + Bt 8KB)
  int b = (blockIdx.x & 7) * 80 + (blockIdx.x >> 3);   // bijective XCD swizzle (640 = 8*80)
  const u16* Bp; int which;    // 0=Q 1=K 2=V
  if (b < 256)      { Bp = wqb; which = 0; }
  else if (b < 512) { Bp = wkb; which = 1; b -= 256; }
  else              { Bp = wvb; which = 2; b -= 512; }
  int sh = (which == 2) ? 3 : 4;
  int m0 = (b >> sh) * 128, n0 = (b & ((1 << sh) - 1)) * 128;

  f4v acc[4][4];
  gemm_core(xb, Bp, 1024, m0, n0, lds, acc);

  const int l = threadIdx.x & 63, w = threadIdx.x >> 6;
  const int wrow = (w >> 1) * 64, wcol = (w & 1) * 64;
  if (which < 2){
    u16* C = which ? kf : qf;
    #pragma unroll
    for (int mr = 0; mr < 4; mr++)
      #pragma unroll
      for (int nc = 0; nc < 4; nc++)
        #pragma unroll
        for (int rr = 0; rr < 4; rr++){
          int row = m0 + wrow + mr * 16 + (l >> 4) * 4 + rr;
          int col = n0 + wcol + nc * 16 + (l & 15);
          C[(size_t)row * 2048 + col] = f2b(acc[mr][nc][rr]);
        }
  } else {
    // transposed store: vtb[h][d][t], 4 consecutive t packed per uint2
    #pragma unroll
    for (int mr = 0; mr < 4; mr++)
      #pragma unroll
      for (int nc = 0; nc < 4; nc++){
        int gcol = n0 + wcol + nc * 16 + (l & 15);
        int t0 = m0 + wrow + mr * 16 + (l >> 4) * 4;
        uint2 pk;
        pk.x = (u32)f2b(acc[mr][nc][0]) | ((u32)f2b(acc[mr][nc][1]) << 16);
        pk.y = (u32)f2b(acc[mr][nc][2]) | ((u32)f2b(acc[mr][nc][3]) << 16);
        *(uint2*)(vtb + (size_t)gcol * 2048 + t0) = pk;   // gcol = h*64+d
      }
  }
}

__global__ __launch_bounds__(256) void o_gemm(const u16* __restrict__ yb, const u16* __restrict__ wob,
                                              float* out){
  __shared__ u16 lds[40960];
  int b = (blockIdx.x & 7) * 16 + (blockIdx.x >> 3);   // 128 = 8*16
  int m0 = (b >> 3) * 128, n0 = (b & 7) * 128;
  f4v acc[4][4];
  gemm_core(yb, wob, 1024, m0, n0, lds, acc);
  const int l = threadIdx.x & 63, w = threadIdx.x >> 6;
  const int wrow = (w >> 1) * 64, wcol = (w & 1) * 64;
  #pragma unroll
  for (int mr = 0; mr < 4; mr++)
    #pragma unroll
    for (int nc = 0; nc < 4; nc++)
      #pragma unroll
      for (int rr = 0; rr < 4; rr++){
        int row = m0 + wrow + mr * 16 + (l >> 4) * 4 + rr;
        int col = n0 + wcol + nc * 16 + (l & 15);
        out[(size_t)row * 1024 + col] = acc[mr][nc][rr];
      }
}

// ---------------- merged ReLU + top-32-of-128 (bf16 inputs, 15-bit radix) ----------------
__global__ __launch_bounds__(256) void topk2(const u16* __restrict__ qf, const u16* __restrict__ kf,
                                             u16* __restrict__ qsb, u16* __restrict__ ksb){
  int w = threadIdx.x >> 6, l = threadIdx.x & 63;
  int b = blockIdx.x;
  const u16* src; u16* dst;
  if (b < 8192){ src = qf; dst = qsb; } else { src = kf; dst = ksb; b -= 8192; }
  int row = b * 4 + w;
  int t = row >> 4, h = row & 15;
  u32 pair = ((const u32*)(src + (size_t)t * 2048 + h * 128))[l];
  u32 u0 = pair & 0xFFFFu, u1 = pair >> 16;
  if (u0 & 0x8000u) u0 = 0;   // ReLU (negative bf16 -> 0)
  if (u1 & 0x8000u) u1 = 0;
  u32 pre = 0;
  for (int bb = 14; bb >= 0; --bb){
    u32 cand = pre | (1u << bb);
    int c = __builtin_popcountll(__ballot(u0 >= cand)) + __builtin_popcountll(__ballot(u1 >= cand));
    if (c >= 32) pre = cand;
  }
  u32 o0 = (u0 >= pre) ? u0 : 0u;
  u32 o1 = (u1 >= pre) ? u1 : 0u;
  ((u32*)(dst + ((size_t)h * 2048 + t) * 128))[l] = o0 | (o1 << 16);
}

// ---------------- chunk-parallel causal p=1 attention (8 waves, dbuf, gload_lds) ----------------
__global__ __launch_bounds__(512) void attn3(const u16* __restrict__ qs, const u16* __restrict__ ks,
                                             const u16* __restrict__ vt, const float* __restrict__ sink,
                                             const float* __restrict__ logbeta, u16* __restrict__ yout,
                                             float* __restrict__ Yp, float* __restrict__ Dp){
  __shared__ u16 Kt[2][8192];
  __shared__ u16 Vt[2][4096];
  __shared__ u16 St[8][16 * 72];
  const int tid = threadIdx.x, l = tid & 63, w = tid >> 6;
  const int b = blockIdx.x;
  const int slot = b >> 3;
  const int h = (b & 7) + 8 * (slot / 40);
  const int u = slot % 40;
  int it, chunk, nch;
  if (u < 4)       { it = u; chunk = 0; nch = 1; }
  else if (u < 12) { it = 4 + ((u - 4) >> 1);  chunk = (u - 4) & 1;  nch = 2; }
  else if (u < 24) { it = 8 + (u - 12) / 3;    chunk = (u - 12) % 3; nch = 3; }
  else             { it = 12 + ((u - 24) >> 2); chunk = (u - 24) & 3; nch = 4; }
  const int jt0 = chunk * 8;
  const int jt1 = min(jt0 + 8, 2 * it + 2);
  const int qrow0 = it * 128 + w * 16;
  const float beta = expf(logbeta[0]);

  bf8v qfr[4];
  {
    int trow = qrow0 + (l & 15);
    const u16* qrow = qs + ((size_t)h * 2048 + trow) * 128 + (l >> 4) * 8;
    #pragma unroll
    for (int kk = 0; kk < 4; kk++) qfr[kk] = *(const bf8v*)(qrow + kk * 32);
  }

  f4v accY[4];
  #pragma unroll
  for (int c = 0; c < 4; c++) accY[c] = (f4v)0.0f;
  float dsum[4] = {0.f, 0.f, 0.f, 0.f};

  const u16* kroot = ks + (size_t)h * 2048 * 128;
  const u16* vroot = vt + (size_t)h * 64 * 2048;

  auto stage = [&](int jt, int buf){
    const u16* kbase = kroot + (size_t)jt * 64 * 128;
    #pragma unroll
    for (int i = 0; i < 2; i++){
      int g = i * 512 + tid;
      int r = g >> 4, c = g & 15;
      __builtin_amdgcn_global_load_lds((const AS1 void*)(kbase + r * 128 + (c ^ (r & 7)) * 8),
                                       (AS3 void*)(&Kt[buf][(i * 512 + w * 64) * 8]), 16, 0, 0);
    }
    {
      int d = tid >> 3, c = tid & 7;
      __builtin_amdgcn_global_load_lds((const AS1 void*)(vroot + (size_t)d * 2048 + jt * 64 + (c ^ (d & 7)) * 8),
                                       (AS3 void*)(&Vt[buf][w * 512]), 16, 0, 0);
    }
  };

  stage(jt0, 0);
  __syncthreads();
  int buf = 0;
  for (int jt = jt0; jt < jt1; ++jt){
    if (jt + 1 < jt1) stage(jt + 1, buf ^ 1);

    if (jt * 64 <= qrow0 + 15){
      f4v accS[4];
      #pragma unroll
      for (int c = 0; c < 4; c++) accS[c] = (f4v)0.0f;
      __builtin_amdgcn_s_setprio(1);
      #pragma unroll
      for (int c = 0; c < 4; c++){
        int r = c * 16 + (l & 15);
        #pragma unroll
        for (int kk = 0; kk < 4; kk++){
          int ch = kk * 4 + (l >> 4);
          bf8v kfr = *(const bf8v*)(&Kt[buf][r * 128 + ((ch ^ (r & 7)) * 8)]);
          accS[c] = __builtin_amdgcn_mfma_f32_16x16x32_bf16(qfr[kk], kfr, accS[c], 0, 0, 0);
        }
      }
      __builtin_amdgcn_s_setprio(0);
      if (jt * 64 + 63 > qrow0){
        #pragma unroll
        for (int c = 0; c < 4; c++)
          #pragma unroll
          for (int rr = 0; rr < 4; rr++){
            int i = qrow0 + (l >> 4) * 4 + rr;
            int j = jt * 64 + c * 16 + (l & 15);
            if (j > i) accS[c][rr] = 0.f;
          }
      }
      #pragma unroll
      for (int c = 0; c < 4; c++)
        #pragma unroll
        for (int rr = 0; rr < 4; rr++){
          dsum[rr] += accS[c][rr];
          St[w][((l >> 4) * 4 + rr) * 72 + c * 16 + (l & 15)] = f2b(accS[c][rr]);
        }
      __builtin_amdgcn_s_setprio(1);
      #pragma unroll
      for (int k2 = 0; k2 < 2; k2++){
        bf8v afr = *(const bf8v*)(&St[w][(l & 15) * 72 + k2 * 32 + (l >> 4) * 8]);
        #pragma unroll
        for (int c = 0; c < 4; c++){
          int d = c * 16 + (l & 15);
          int ch = k2 * 4 + (l >> 4);
          bf8v vfr = *(const bf8v*)(&Vt[buf][d * 64 + ((ch ^ (d & 7)) * 8)]);
          accY[c] = __builtin_amdgcn_mfma_f32_16x16x32_bf16(afr, vfr, accY[c], 0, 0, 0);
        }
      }
      __builtin_amdgcn_s_setprio(0);
    }
    __syncthreads();
    buf ^= 1;
  }

  #pragma unroll
  for (int rr = 0; rr < 4; rr++){
    float s = dsum[rr];
    s += __shfl_xor(s, 1, 64);
    s += __shfl_xor(s, 2, 64);
    s += __shfl_xor(s, 4, 64);
    s += __shfl_xor(s, 8, 64);
    dsum[rr] = s;
  }

  if (nch == 1){
    #pragma unroll
    for (int c = 0; c < 4; c++){
      float sv = sink[h * 64 + c * 16 + (l & 15)];
      #pragma unroll
      for (int rr = 0; rr < 4; rr++){
        float den = dsum[rr] + beta;
        float inv = 1.0f / fmaxf(den, 1e-12f);
        float y = (accY[c][rr] + beta * sv) * inv;
        int row = qrow0 + (l >> 4) * 4 + rr;
        yout[(size_t)row * 1024 + h * 64 + c * 16 + (l & 15)] = f2b(y);
      }
    }
  } else {
    float* yp = Yp + ((size_t)h * 40 + u) * 8192;
    #pragma unroll
    for (int c = 0; c < 4; c++)
      #pragma unroll
      for (int rr = 0; rr < 4; rr++){
        int rowib = w * 16 + (l >> 4) * 4 + rr;
        yp[rowib * 64 + c * 16 + (l & 15)] = accY[c][rr];
      }
    if ((l & 15) == 0){
      #pragma unroll
      for (int rr = 0; rr < 4; rr++)
        Dp[((size_t)h * 40 + u) * 128 + w * 16 + (l >> 4) * 4 + rr] = dsum[rr];
    }
  }
}

// combine partials for it 4..15 (grid 16 x 12)
__global__ __launch_bounds__(256) void attn_reduce(const float* __restrict__ Yp, const float* __restrict__ Dp,
                                                   const float* __restrict__ sink, const float* __restrict__ logbeta,
                                                   u16* __restrict__ yout){
  int blk = blockIdx.x;
  int h = blk / 12, it = 4 + blk % 12;
  int nch = it / 4 + 1;
  int u0 = (it < 8) ? 4 + (it - 4) * 2 : (it < 12) ? 12 + (it - 8) * 3 : 24 + (it - 12) * 4;
  float beta = expf(logbeta[0]);
  __shared__ float inv_s[128];
  int t = threadIdx.x;
  if (t < 128){
    float s = 0.f;
    for (int c = 0; c < nch; c++) s += Dp[((size_t)h * 40 + u0 + c) * 128 + t];
    inv_s[t] = 1.0f / fmaxf(s + beta, 1e-12f);
  }
  __syncthreads();
  const float* base = Yp + ((size_t)h * 40 + u0) * 8192;
  #pragma unroll
  for (int e = 0; e < 32; e++){
    int idx = e * 256 + t;
    float acc = 0.f;
    for (int c = 0; c < nch; c++) acc += base[c * 8192 + idx];
    int row = idx >> 6, col = idx & 63;
    float y = (acc + beta * sink[h * 64 + col]) * inv_s[row];
    yout[(size_t)(it * 128 + row) * 1024 + h * 64 + col] = f2b(y);
  }
}

extern "C" void kernel_launch(void* const* d_in, const int* in_sizes, int n_in,
                              void* d_out, int out_size, void* d_ws, size_t ws_size,
                              hipStream_t stream){
  const float* x    = (const float*)d_in[0];
  const float* Wq   = (const float*)d_in[1];
  const float* Wk   = (const float*)d_in[2];
  const float* Wv   = (const float*)d_in[3];
  const float* Wo   = (const float*)d_in[4];
  const float* sink = (const float*)d_in[5];
  const float* logb = (const float*)d_in[6];

  char* ws = (char*)d_ws;
  u16*   xb  = (u16*)(ws + 0);            // 4 MB
  u16*   wqb = (u16*)(ws + 4194304);      // 4 MB
  u16*   wkb = (u16*)(ws + 8388608);      // 4 MB
  u16*   wvb = (u16*)(ws + 12582912);     // 2 MB
  u16*   wob = (u16*)(ws + 14680064);     // 2 MB
  u16*   qf  = (u16*)(ws + 16777216);     // 8 MB bf16 scores (live: qkv_gemm -> topk2)
  u16*   kf  = (u16*)(ws + 33554432);     // 8 MB bf16 scores (live: qkv_gemm -> topk2)
  u16*   qsb = (u16*)(ws + 50331648);     // 8 MB  [16][2048][128]
  u16*   ksb = (u16*)(ws + 58720256);     // 8 MB
  u16*   vtb = (u16*)(ws + 67108864);     // 4 MB  V^T [16][64][2048]
  u16*   yb  = (u16*)(ws + 71303168);     // 4 MB  [2048][1024]
  float* Yp  = (float*)(ws + 16777216);   // 21 MB partials (overlays qf/kf AFTER topk2)
  float* Dp  = (float*)(ws + 37748736);   // 320 KB (dead kf region, after topk2)

  conv_all<<<8192, 256, 0, stream>>>(x, Wq, Wk, Wv, Wo, xb, wqb, wkb, wvb, wob);
  qkv_gemm<<<640, 256, 0, stream>>>(xb, wqb, wkb, wvb, qf, kf, vtb);
  topk2<<<16384, 256, 0, stream>>>(qf, kf, qsb, ksb);
  attn3<<<640, 512, 0, stream>>>(qsb, ksb, vtb, sink, logb, yb, Yp, Dp);
  attn_reduce<<<192, 256, 0, stream>>>(Yp, Dp, sink, logb, yb);
  o_gemm<<<128, 256, 0, stream>>>(yb, wob, (float*)d_out);
}